// Round 6
// baseline (98.752 us; speedup 1.0000x reference)
//
#include <hip/hip_runtime.h>

#define NB_     32
#define NSITES_ 65536
#define NNGB_   13
#define DIM_    3
#define NG_     48
#define GD_     (NG_ * DIM_)   // 144

typedef unsigned uvec4_t __attribute__((ext_vector_type(4)));
typedef int      ivec4_t __attribute__((ext_vector_type(4)));

// ---------------------------------------------------------------------------
// Kernel A (fused prep):
//   blocks [0, nTrans): transpose In (32,65536) f32 -> TWO site-major bf16
//     half-tables of 2 MB each: A = batches 0..15, B = batches 16..31,
//     32-B rows. Rationale: a single 4-MB table equals the entire per-XCD
//     L2, so the gather's out/nn streams evict it and every gather miss
//     pays ~900cy HBM latency at a bounded per-CU miss-slot count (the
//     measured ~1.7 TB/s gather ceiling). A 2-MB table + streams fits in
//     L2 -> misses become ~200cy L2 hits.
//   blocks [nTrans, nTrans+39): one Wmean entry per block.
// ---------------------------------------------------------------------------
__global__ __launch_bounds__(256) void prep_kernel_78486(
    const float* __restrict__ In,
    const float* __restrict__ wtVC,
    const float* __restrict__ gdiags,
    const int*   __restrict__ perms,
    const int*   __restrict__ nn,
    float*  __restrict__ wm,      // 39 floats
    ushort* __restrict__ InTA,    // (65536,16) bf16, batches 0..15
    ushort* __restrict__ InTB,    // (65536,16) bf16, batches 16..31
    int nTransBlocks)
{
    const int t = threadIdx.x;
    if ((int)blockIdx.x < nTransBlocks) {
        const int tb = blockIdx.x;
        const int s0 = tb * 64;

        // nn L3-warm (carried from R5 base; harmless, nn is now read twice).
        int keep = 0;
        if (t < NNGB_ * 16) {
            const int j = t >> 4, i4 = t & 15;
            ivec4_t v = *(const ivec4_t*)(nn + j * NSITES_ + s0 + 4 * i4);
            keep = v.x ^ v.y ^ v.z ^ v.w;
        }

        __shared__ ushort tile[64][40];   // 80-B rows: 16-B aligned reads
        const int sl = t & 63, bq = t >> 6;
#pragma unroll
        for (int r = 0; r < 8; r++) {
            int b = bq * 8 + r;
            float v = In[b * NSITES_ + s0 + sl];
            unsigned fu = __float_as_uint(v);
            fu = fu + 0x7FFFu + ((fu >> 16) & 1u);   // RNE f32->bf16
            tile[sl][b] = (ushort)(fu >> 16);
        }
        __syncthreads();
        const int site = t >> 2, q = t & 3;          // 64 sites x 4 quads
        uvec4_t val = *(const uvec4_t*)&tile[site][q * 8];
        ushort* T = (q < 2) ? InTA : InTB;
        __builtin_nontemporal_store(
            val, (uvec4_t*)(T + ((size_t)(s0 + site) << 4) + ((q & 1) << 3)));
        asm volatile("" :: "v"(keep));               // keep nn loads alive
    } else {
        const int p = blockIdx.x - nTransBlocks;
        const int d = p / NNGB_, j = p - NNGB_ * d;
        __shared__ float wpj[GD_];
        __shared__ float red[4];
        if (t < GD_) {
            int g = t / DIM_, dp = t - DIM_ * g;     // k = g*3+dp = t
            wpj[t] = wtVC[dp * NNGB_ + perms[g * NNGB_ + j]];
        }
        __syncthreads();
        float acc = 0.f;
        for (int e = t; e < NG_ * GD_; e += 256) {   // coalesced over k
            int g = e / GD_;
            int k = e - g * GD_;
            acc += gdiags[(g * DIM_ + d) * GD_ + k] * wpj[k];
        }
#pragma unroll
        for (int off = 32; off > 0; off >>= 1) acc += __shfl_down(acc, off, 64);
        if ((t & 63) == 0) red[t >> 6] = acc;
        __syncthreads();
        if (t == 0) wm[p] = (red[0] + red[1] + red[2] + red[3]) * (1.0f / NG_);
    }
}

// ---------------------------------------------------------------------------
// Kernel B: gather-conv over ONE 2-MB half-table (16 batches).
// thread = (site, half): 2 lanes cover one site's 32-B row; each thread
// handles 8 batches x 3 dims = 24 accumulators — identical compute shape
// to the best-known v1 gather, only the table is half-width.
// All 13 idx loads issue first, then all 13 independent 16-B gathers.
// ---------------------------------------------------------------------------
__global__ __launch_bounds__(256) void gather_half_78486(
    const ushort* __restrict__ T,     // (65536, 16) bf16
    const int*    __restrict__ nn,    // (13, 65536)
    const float*  __restrict__ wm,    // 39
    float* __restrict__ out,          // (32, 3, 65536)
    int bBase)                        // 0 or 16
{
    const int t = blockIdx.x * 256 + threadIdx.x;   // 0..131071
    const int h = t & 1;                            // 16-B half of the row
    const int s = t >> 1;                           // site

    int idx[NNGB_];
#pragma unroll
    for (int j = 0; j < NNGB_; j++) idx[j] = nn[j * NSITES_ + s];

    uvec4_t u[NNGB_];
#pragma unroll
    for (int j = 0; j < NNGB_; j++)
        u[j] = *(const uvec4_t*)(T + ((size_t)idx[j] << 4) + (h << 3));

    float a0[8], a1[8], a2[8];
#pragma unroll
    for (int i = 0; i < 8; i++) { a0[i] = 0.f; a1[i] = 0.f; a2[i] = 0.f; }

#pragma unroll
    for (int j = 0; j < NNGB_; j++) {
        unsigned uu[4] = {u[j].x, u[j].y, u[j].z, u[j].w};
        float v[8];
#pragma unroll
        for (int k = 0; k < 4; k++) {
            v[2 * k]     = __uint_as_float(uu[k] << 16);
            v[2 * k + 1] = __uint_as_float(uu[k] & 0xFFFF0000u);
        }
        float w0 = wm[j], w1 = wm[NNGB_ + j], w2 = wm[2 * NNGB_ + j];
#pragma unroll
        for (int i = 0; i < 8; i++) {
            a0[i] += w0 * v[i];
            a1[i] += w1 * v[i];
            a2[i] += w2 * v[i];
        }
    }

#pragma unroll
    for (int i = 0; i < 8; i++) {
        int b = bBase + h * 8 + i;
        size_t base = (size_t)b * DIM_ * NSITES_ + s;
        out[base]               = a0[i];
        out[base + NSITES_]     = a1[i];
        out[base + 2 * NSITES_] = a2[i];
    }
}

// ---------------------------------------------------------------------------
// Fallback (tiny ws): direct gather from batch-major In fp32.
// ---------------------------------------------------------------------------
__global__ __launch_bounds__(256) void gather_fallback_78486(
    const float* __restrict__ In,
    const int*   __restrict__ nn,
    const float* __restrict__ wm,
    float* __restrict__ out)
{
    const int t = blockIdx.x * 256 + threadIdx.x;
    const int s = t & (NSITES_ - 1);
    const int b = t >> 16;
    float x0 = 0.f, x1 = 0.f, x2 = 0.f;
#pragma unroll
    for (int j = 0; j < NNGB_; j++) {
        int idx = nn[j * NSITES_ + s];
        float v = In[b * NSITES_ + idx];
        x0 += wm[0 * NNGB_ + j] * v;
        x1 += wm[1 * NNGB_ + j] * v;
        x2 += wm[2 * NNGB_ + j] * v;
    }
    out[(b * DIM_ + 0) * NSITES_ + s] = x0;
    out[(b * DIM_ + 1) * NSITES_ + s] = x1;
    out[(b * DIM_ + 2) * NSITES_ + s] = x2;
}

extern "C" void kernel_launch(void* const* d_in, const int* in_sizes, int n_in,
                              void* d_out, int out_size, void* d_ws, size_t ws_size,
                              hipStream_t stream)
{
    const float* In     = (const float*)d_in[0];   // (32,1,65536) f32
    const float* wtVC   = (const float*)d_in[1];   // (3,13) f32
    const float* gdiags = (const float*)d_in[2];   // (144,144) f32
    const int*   perms  = (const int*)d_in[3];     // (48,13) i32
    const int*   nn     = (const int*)d_in[4];     // (13,65536) i32
    float* out = (float*)d_out;

    float*  wm   = (float*)d_ws;                              // 39 floats
    ushort* InTA = (ushort*)((char*)d_ws + 1024);             // 2 MB
    ushort* InTB = (ushort*)((char*)d_ws + 1024 +
                             (size_t)NSITES_ * 16 * sizeof(ushort));  // 2 MB

    const size_t need = 1024 + (size_t)NSITES_ * NB_ * sizeof(ushort);
    const int nTrans = NSITES_ / 64;                          // 1024

    if (ws_size >= need) {
        prep_kernel_78486<<<nTrans + DIM_ * NNGB_, 256, 0, stream>>>(
            In, wtVC, gdiags, perms, nn, wm, InTA, InTB, nTrans);
        gather_half_78486<<<(NSITES_ * 2) / 256, 256, 0, stream>>>(
            InTA, nn, wm, out, 0);
        gather_half_78486<<<(NSITES_ * 2) / 256, 256, 0, stream>>>(
            InTB, nn, wm, out, 16);
    } else {
        prep_kernel_78486<<<DIM_ * NNGB_, 256, 0, stream>>>(
            In, wtVC, gdiags, perms, nn, wm, (ushort*)nullptr,
            (ushort*)nullptr, 0);
        gather_fallback_78486<<<(NSITES_ * NB_) / 256, 256, 0, stream>>>(
            In, nn, wm, out);
    }
}

// Round 7
// 92.811 us; speedup vs baseline: 1.0640x; 1.0640x over previous
//
#include <hip/hip_runtime.h>

#define NB_     32
#define NSITES_ 65536
#define NNGB_   13
#define DIM_    3
#define NG_     48
#define GD_     (NG_ * DIM_)   // 144

typedef unsigned uvec4_t __attribute__((ext_vector_type(4)));
typedef int      ivec4_t __attribute__((ext_vector_type(4)));

// ---------------------------------------------------------------------------
// Kernel A (fused prep):
//   blocks [0, nTrans):        transpose In (32,65536) f32 -> InT (65536,32)
//                              bf16, NT stores; also L3-warms this block's
//                              nn slice for the gather kernel.
//   blocks [nTrans, nTrans+39): one Wmean entry per block.
// (Best-known configuration: 93.10 us measured in Round 5.)
// ---------------------------------------------------------------------------
__global__ __launch_bounds__(256) void prep_kernel_78486(
    const float* __restrict__ In,
    const float* __restrict__ wtVC,
    const float* __restrict__ gdiags,
    const int*   __restrict__ perms,
    const int*   __restrict__ nn,
    float*  __restrict__ wm,      // 39 floats
    ushort* __restrict__ InT,     // 65536*32 bf16 (null in fallback)
    int nTransBlocks)
{
    const int t = threadIdx.x;
    if ((int)blockIdx.x < nTransBlocks) {
        const int tb = blockIdx.x;
        const int s0 = tb * 64;

        // nn L3-warm: 13 j x 64 sites, int4 loads, kept live via asm
        // (rule #17: prevents DCE without a store).
        int keep = 0;
        if (t < NNGB_ * 16) {
            const int j = t >> 4, i4 = t & 15;
            ivec4_t v = *(const ivec4_t*)(nn + j * NSITES_ + s0 + 4 * i4);
            keep = v.x ^ v.y ^ v.z ^ v.w;
        }

        __shared__ ushort tile[64][40];   // 80-B rows: 16-B aligned reads
        const int sl = t & 63, bq = t >> 6;
#pragma unroll
        for (int r = 0; r < 8; r++) {
            int b = bq * 8 + r;
            float v = In[b * NSITES_ + s0 + sl];
            unsigned fu = __float_as_uint(v);
            fu = fu + 0x7FFFu + ((fu >> 16) & 1u);   // RNE f32->bf16
            tile[sl][b] = (ushort)(fu >> 16);
        }
        __syncthreads();
        const int site = t >> 2, q = t & 3;          // 64 sites x 4 quads
        uvec4_t val = *(const uvec4_t*)&tile[site][q * 8];
        __builtin_nontemporal_store(
            val, (uvec4_t*)(InT + (size_t)(s0 + site) * NB_ + q * 8));
        asm volatile("" :: "v"(keep));               // keep nn loads alive
    } else {
        const int p = blockIdx.x - nTransBlocks;
        const int d = p / NNGB_, j = p - NNGB_ * d;
        __shared__ float wpj[GD_];
        __shared__ float red[4];
        if (t < GD_) {
            int g = t / DIM_, dp = t - DIM_ * g;     // k = g*3+dp = t
            wpj[t] = wtVC[dp * NNGB_ + perms[g * NNGB_ + j]];
        }
        __syncthreads();
        float acc = 0.f;
        for (int e = t; e < NG_ * GD_; e += 256) {   // coalesced over k
            int g = e / GD_;
            int k = e - g * GD_;
            acc += gdiags[(g * DIM_ + d) * GD_ + k] * wpj[k];
        }
#pragma unroll
        for (int off = 32; off > 0; off >>= 1) acc += __shfl_down(acc, off, 64);
        if ((t & 63) == 0) red[t >> 6] = acc;
        __syncthreads();
        if (t == 0) wm[p] = (red[0] + red[1] + red[2] + red[3]) * (1.0f / NG_);
    }
}

// ---------------------------------------------------------------------------
// Kernel B: gather-conv — best-known v1 structure.
// thread = (site, quarter): 4 lanes cover one site's 64-B InT row; each
// thread handles 8 batches x 3 dims = 24 accumulators. All 13 idx loads
// issue first, then all 13 independent 16-B gathers (208 B/lane in flight).
// Gather floor: 8 XCDs x 65536 compulsory line-misses, MSHR-latency-bound
// (~25-33 us) — invariant to threading/policy/residency (R2/R3/R5/R6 nulls).
// ---------------------------------------------------------------------------
__global__ __launch_bounds__(256) void gather_kernel_78486(
    const ushort* __restrict__ InT,
    const int*    __restrict__ nn,    // (13, 65536)
    const float*  __restrict__ wm,    // 39
    float* __restrict__ out)          // (32, 3, 65536)
{
    const int t = blockIdx.x * 256 + threadIdx.x;   // 0..262143
    const int q = t & 3;                            // batch quarter
    const int s = t >> 2;                           // site

    int idx[NNGB_];
#pragma unroll
    for (int j = 0; j < NNGB_; j++) idx[j] = nn[j * NSITES_ + s];

    uvec4_t u[NNGB_];
#pragma unroll
    for (int j = 0; j < NNGB_; j++)
        u[j] = *(const uvec4_t*)(InT + ((size_t)idx[j] << 5) + (q << 3));

    float a0[8], a1[8], a2[8];
#pragma unroll
    for (int i = 0; i < 8; i++) { a0[i] = 0.f; a1[i] = 0.f; a2[i] = 0.f; }

#pragma unroll
    for (int j = 0; j < NNGB_; j++) {
        unsigned uu[4] = {u[j].x, u[j].y, u[j].z, u[j].w};
        float v[8];
#pragma unroll
        for (int k = 0; k < 4; k++) {
            v[2 * k]     = __uint_as_float(uu[k] << 16);
            v[2 * k + 1] = __uint_as_float(uu[k] & 0xFFFF0000u);
        }
        float w0 = wm[j], w1 = wm[NNGB_ + j], w2 = wm[2 * NNGB_ + j];
#pragma unroll
        for (int i = 0; i < 8; i++) {
            a0[i] += w0 * v[i];
            a1[i] += w1 * v[i];
            a2[i] += w2 * v[i];
        }
    }

#pragma unroll
    for (int i = 0; i < 8; i++) {
        int b = q * 8 + i;
        size_t base = (size_t)b * DIM_ * NSITES_ + s;
        out[base]               = a0[i];
        out[base + NSITES_]     = a1[i];
        out[base + 2 * NSITES_] = a2[i];
    }
}

// ---------------------------------------------------------------------------
// Fallback (tiny ws): direct gather from batch-major In fp32.
// ---------------------------------------------------------------------------
__global__ __launch_bounds__(256) void gather_fallback_78486(
    const float* __restrict__ In,
    const int*   __restrict__ nn,
    const float* __restrict__ wm,
    float* __restrict__ out)
{
    const int t = blockIdx.x * 256 + threadIdx.x;
    const int s = t & (NSITES_ - 1);
    const int b = t >> 16;
    float x0 = 0.f, x1 = 0.f, x2 = 0.f;
#pragma unroll
    for (int j = 0; j < NNGB_; j++) {
        int idx = nn[j * NSITES_ + s];
        float v = In[b * NSITES_ + idx];
        x0 += wm[0 * NNGB_ + j] * v;
        x1 += wm[1 * NNGB_ + j] * v;
        x2 += wm[2 * NNGB_ + j] * v;
    }
    out[(b * DIM_ + 0) * NSITES_ + s] = x0;
    out[(b * DIM_ + 1) * NSITES_ + s] = x1;
    out[(b * DIM_ + 2) * NSITES_ + s] = x2;
}

extern "C" void kernel_launch(void* const* d_in, const int* in_sizes, int n_in,
                              void* d_out, int out_size, void* d_ws, size_t ws_size,
                              hipStream_t stream)
{
    const float* In     = (const float*)d_in[0];   // (32,1,65536) f32
    const float* wtVC   = (const float*)d_in[1];   // (3,13) f32
    const float* gdiags = (const float*)d_in[2];   // (144,144) f32
    const int*   perms  = (const int*)d_in[3];     // (48,13) i32
    const int*   nn     = (const int*)d_in[4];     // (13,65536) i32
    float* out = (float*)d_out;

    float*  wm  = (float*)d_ws;                          // 39 floats
    ushort* InT = (ushort*)((char*)d_ws + 1024);         // 4 MB bf16

    const size_t need = 1024 + (size_t)NSITES_ * NB_ * sizeof(ushort);
    const int nTrans = NSITES_ / 64;                     // 1024

    if (ws_size >= need) {
        prep_kernel_78486<<<nTrans + DIM_ * NNGB_, 256, 0, stream>>>(
            In, wtVC, gdiags, perms, nn, wm, InT, nTrans);
        gather_kernel_78486<<<(NSITES_ * 4) / 256, 256, 0, stream>>>(
            InT, nn, wm, out);
    } else {
        prep_kernel_78486<<<DIM_ * NNGB_, 256, 0, stream>>>(
            In, wtVC, gdiags, perms, nn, wm, (ushort*)nullptr, 0);
        gather_fallback_78486<<<(NSITES_ * NB_) / 256, 256, 0, stream>>>(
            In, nn, wm, out);
    }
}